// Round 2
// baseline (1006.102 us; speedup 1.0000x reference)
//
#include <hip/hip_runtime.h>
#include <stdint.h>

// Problem dims (fixed by reference setup_inputs)
#define B_   32
#define T_   2048
#define I_   512
#define H_   16
#define D_   64
#define BT   (B_*T_)        // 65536 rows
#define NCOL (3*H_*D_)      // 3072 gemm cols: col' = kk*1024 + h*64 + d  (kk: 0=k,1=v,2=q)
#define CCH  64             // chunks per (b,h) chain
#define LCH  (T_/CCH)       // 32 timesteps per chunk

typedef short short8 __attribute__((ext_vector_type(8)));
typedef float floatx4 __attribute__((ext_vector_type(4)));

__device__ __forceinline__ unsigned short f2bf(float f) {
    uint32_t u = __float_as_uint(f);
    u = (u + 0x7FFFu + ((u >> 16) & 1u)) >> 16;   // RNE
    return (unsigned short)u;
}
__device__ __forceinline__ float bf2f(unsigned short u) {
    return __uint_as_float(((uint32_t)u) << 16);
}

// ---------------- Pass 0a: x fp32 -> bf16 ----------------
__global__ __launch_bounds__(256) void k_convert_x(const float* __restrict__ x,
                                                   unsigned short* __restrict__ xb) {
    int i = blockIdx.x * 256 + threadIdx.x;        // over n/4 exactly
    float4 v = ((const float4*)x)[i];
    ushort4 o;
    o.x = f2bf(v.x); o.y = f2bf(v.y); o.z = f2bf(v.z); o.w = f2bf(v.w);
    ((ushort4*)xb)[i] = o;
}

// ---------------- Pass 0b: W (I,H,D,3) fp32 -> Wt (3072 x 512) bf16, col-major repack ----------------
__global__ __launch_bounds__(256) void k_repack_w(const float* __restrict__ W,
                                                  unsigned short* __restrict__ Wt) {
    int idx = blockIdx.x * 256 + threadIdx.x;      // over I*H*D*3
    if (idx >= I_ * H_ * D_ * 3) return;
    int kk = idx % 3;
    int d  = (idx / 3) % D_;
    int h  = (idx / (3 * D_)) % H_;
    int i  = idx / (3 * D_ * H_);
    int col = kk * (H_ * D_) + h * D_ + d;         // kk*1024 + h*64 + d
    Wt[(size_t)col * I_ + i] = f2bf(W[idx]);
}

// ---------------- Pass 1: GEMM  C[BT][3072] = A[BT][512] * Wt^T  (bf16 MFMA, 128x128 tile, BK=32) ----------------
__device__ __forceinline__ void load_lds16(const void* g, void* l) {
    __builtin_amdgcn_global_load_lds((const __attribute__((address_space(1))) unsigned int*)g,
                                     (__attribute__((address_space(3))) unsigned int*)l, 16, 0, 0);
}

__global__ __launch_bounds__(256) void k_gemm(const unsigned short* __restrict__ A,
                                              const unsigned short* __restrict__ Bt,
                                              unsigned short* __restrict__ C) {
    __shared__ unsigned short Alds[128 * 32];
    __shared__ unsigned short Blds[128 * 32];   // stored as [n'][k]
    const int tid  = threadIdx.x;
    const int lane = tid & 63;
    const int wave = tid >> 6;
    const int wr = wave >> 1, wc = wave & 1;
    const int cb = blockIdx.x;                  // 0..23  (fastest-varying -> A tiles L2-resident)
    const int rb = blockIdx.y;                  // 0..511
    const int l15 = lane & 15;
    const int kh  = lane >> 4;                  // 0..3

    floatx4 acc[4][4] = {};

    for (int ko = 0; ko < 16; ++ko) {
        const int k0 = ko * 32;
        // stage A and B tiles: each lane loads 16B; LDS dest linear per wave
        #pragma unroll
        for (int it = 0; it < 2; ++it) {
            int lin = it * 256 + wave * 64 + lane;
            int r = lin >> 2;                   // row within tile
            int c = (lin & 3) << 3;             // k within BK
            const unsigned short* srcA = A  + (size_t)(rb * 128 + r) * I_ + k0 + c;
            const unsigned short* srcB = Bt + (size_t)(cb * 128 + r) * I_ + k0 + c;
            load_lds16(srcA, (void*)(Alds + (size_t)(it * 256 + wave * 64) * 8));
            load_lds16(srcB, (void*)(Blds + (size_t)(it * 256 + wave * 64) * 8));
        }
        __syncthreads();

        short8 af[4], bf[4];
        #pragma unroll
        for (int m = 0; m < 4; ++m)
            af[m] = *(const short8*)(Alds + (size_t)(wr * 64 + m * 16 + l15) * 32 + kh * 8);
        #pragma unroll
        for (int n = 0; n < 4; ++n)
            bf[n] = *(const short8*)(Blds + (size_t)(wc * 64 + n * 16 + l15) * 32 + kh * 8);
        #pragma unroll
        for (int m = 0; m < 4; ++m)
            #pragma unroll
            for (int n = 0; n < 4; ++n)
                acc[m][n] = __builtin_amdgcn_mfma_f32_16x16x32_bf16(af[m], bf[n], acc[m][n], 0, 0, 0);
        __syncthreads();
    }

    // epilogue: C/D layout col=lane&15, row=(lane>>4)*4+reg
    #pragma unroll
    for (int m = 0; m < 4; ++m) {
        #pragma unroll
        for (int n = 0; n < 4; ++n) {
            int ccol = cb * 128 + wc * 64 + n * 16 + l15;
            size_t rrow = (size_t)rb * 128 + wr * 64 + m * 16 + kh * 4;
            #pragma unroll
            for (int reg = 0; reg < 4; ++reg)
                C[(rrow + reg) * NCOL + ccol] = f2bf(acc[m][n][reg]);
        }
    }
}

// ---------------- Pass 2: chunk-local scan -> summaries (m, den, num[64]) ----------------
__global__ __launch_bounds__(256) void k_scan1(const unsigned short* __restrict__ kvq,
                                               float* __restrict__ m_arr,
                                               float* __restrict__ d_arr,
                                               float* __restrict__ n_arr) {
    const int wave = threadIdx.x >> 6, lane = threadIdx.x & 63;
    const int chain = blockIdx.x * 4 + wave;     // (b*16+h)*64 + c
    const int c  = chain & (CCH - 1);
    const int bh = chain >> 6;
    const int h  = bh & (H_ - 1);
    const int b  = bh >> 4;

    float m = -INFINITY, den = 0.f, n = 0.f;
    size_t base = ((size_t)b * T_ + c * LCH) * NCOL + h * D_ + lane;
    #pragma unroll 4
    for (int tl = 0; tl < LCH; ++tl) {
        float kd = bf2f(kvq[base]);
        float vd = bf2f(kvq[base + 1024]);
        float qd = bf2f(kvq[base + 2048]);
        float s = qd * kd;
        #pragma unroll
        for (int off = 32; off; off >>= 1) s += __shfl_xor(s, off);
        float cmax = fmaxf(m, s);
        float md = __expf(m - cmax);
        float sm = __expf(s - cmax);
        den = den * md + sm;
        n   = n * md + vd * sm;
        m = cmax;
        base += NCOL;
    }
    if (lane == 0) { m_arr[chain] = m; d_arr[chain] = den; }
    n_arr[(size_t)chain * 64 + lane] = n;
}

// ---------------- Pass 3: exclusive prefix scan over chunks, per (b,h) ----------------
__global__ __launch_bounds__(256) void k_prefix(const float* __restrict__ m_arr,
                                                const float* __restrict__ d_arr,
                                                const float* __restrict__ n_arr,
                                                float* __restrict__ pm,
                                                float* __restrict__ pd,
                                                float* __restrict__ pn) {
    const int wave = threadIdx.x >> 6, lane = threadIdx.x & 63;
    const int bh = blockIdx.x * 4 + wave;        // 0..511
    float m = -INFINITY, den = 0.f, n = 0.f;
    for (int c = 0; c < CCH; ++c) {
        int idx = bh * CCH + c;
        if (lane == 0) { pm[idx] = m; pd[idx] = den; }
        pn[(size_t)idx * 64 + lane] = n;
        float mc = m_arr[idx], dc = d_arr[idx];
        float nc = n_arr[(size_t)idx * 64 + lane];
        float mn = fmaxf(m, mc);
        float a1 = __expf(m - mn), a2 = __expf(mc - mn);
        den = den * a1 + dc * a2;
        n   = n * a1 + nc * a2;
        m = mn;
    }
}

// ---------------- Pass 4: replay chunks with prefix state, sum over heads, write out ----------------
__global__ __launch_bounds__(1024) void k_scan2(const unsigned short* __restrict__ kvq,
                                                const float* __restrict__ pm,
                                                const float* __restrict__ pd,
                                                const float* __restrict__ pn,
                                                float* __restrict__ out) {
    __shared__ float accum[LCH * 64];            // 8 KB
    const int tid = threadIdx.x;
    const int h = tid >> 6, lane = tid & 63;
    const int bc = blockIdx.x;                   // b*64 + c
    const int c = bc & (CCH - 1), b = bc >> 6;

    accum[tid] = 0.f;
    accum[tid + 1024] = 0.f;
    __syncthreads();

    const int chain = (b * H_ + h) * CCH + c;
    float m = pm[chain], den = pd[chain];
    float n = pn[(size_t)chain * 64 + lane];
    size_t base = ((size_t)b * T_ + c * LCH) * NCOL + h * D_ + lane;
    #pragma unroll 4
    for (int tl = 0; tl < LCH; ++tl) {
        float kd = bf2f(kvq[base]);
        float vd = bf2f(kvq[base + 1024]);
        float qd = bf2f(kvq[base + 2048]);
        float s = qd * kd;
        #pragma unroll
        for (int off = 32; off; off >>= 1) s += __shfl_xor(s, off);
        float cmax = fmaxf(m, s);
        float md = __expf(m - cmax);
        float sm = __expf(s - cmax);
        den = den * md + sm;
        n   = n * md + vd * sm;
        m = cmax;
        atomicAdd(&accum[tl * 64 + lane], n / den);
        base += NCOL;
    }
    __syncthreads();

    size_t ob = ((size_t)b * T_ + c * LCH) * 64;
    out[ob + tid] = accum[tid];
    out[ob + 1024 + tid] = accum[tid + 1024];
}

// ---------------- launch ----------------
extern "C" void kernel_launch(void* const* d_in, const int* in_sizes, int n_in,
                              void* d_out, int out_size, void* d_ws, size_t ws_size,
                              hipStream_t stream) {
    const float* x = (const float*)d_in[0];
    const float* W = (const float*)d_in[1];
    float* out = (float*)d_out;
    char* ws = (char*)d_ws;

    // workspace layout (bytes)
    unsigned short* kvq = (unsigned short*)(ws);                 // 402,653,184
    unsigned short* xb  = (unsigned short*)(ws + 402653184ull);  //  67,108,864
    unsigned short* Wt  = (unsigned short*)(ws + 469762048ull);  //   3,145,728
    float* m_arr = (float*)(ws + 472907776ull);                  //     131,072
    float* d_arr = (float*)(ws + 473038848ull);                  //     131,072
    float* n_arr = (float*)(ws + 473169920ull);                  //   8,388,608
    float* pm    = (float*)(ws + 481558528ull);                  //     131,072
    float* pd    = (float*)(ws + 481689600ull);                  //     131,072
    float* pn    = (float*)(ws + 481820672ull);                  //   8,388,608  -> end 490,209,280

    k_convert_x<<<(BT * I_ / 4) / 256, 256, 0, stream>>>(x, xb);
    k_repack_w<<<(I_ * H_ * D_ * 3 + 255) / 256, 256, 0, stream>>>(W, Wt);
    k_gemm<<<dim3(NCOL / 128, BT / 128), 256, 0, stream>>>(xb, Wt, kvq);
    k_scan1<<<(B_ * H_ * CCH) / 4, 256, 0, stream>>>(kvq, m_arr, d_arr, n_arr);
    k_prefix<<<(B_ * H_) / 4, 256, 0, stream>>>(m_arr, d_arr, n_arr, pm, pd, pn);
    k_scan2<<<B_ * CCH, 1024, 0, stream>>>(kvq, pm, pd, pn, out);
}

// Round 3
// 966.184 us; speedup vs baseline: 1.0413x; 1.0413x over previous
//
#include <hip/hip_runtime.h>
#include <stdint.h>

// Problem dims (fixed by reference setup_inputs)
#define B_   32
#define T_   2048
#define I_   512
#define H_   16
#define D_   64
#define BT   (B_*T_)        // 65536 rows
#define NCOL (3*H_*D_)      // 3072 gemm cols: col' = kk*1024 + h*64 + d  (kk: 0=k,1=v,2=q)
#define CCH  64             // chunks per (b,h) chain
#define LCH  (T_/CCH)       // 32 timesteps per chunk

typedef short short8 __attribute__((ext_vector_type(8)));
typedef float floatx4 __attribute__((ext_vector_type(4)));

__device__ __forceinline__ unsigned short f2bf(float f) {
    uint32_t u = __float_as_uint(f);
    u = (u + 0x7FFFu + ((u >> 16) & 1u)) >> 16;   // RNE
    return (unsigned short)u;
}
__device__ __forceinline__ float bf2f(unsigned short u) {
    return __uint_as_float(((uint32_t)u) << 16);
}

// ---------------- Pass 0a: x fp32 -> bf16 ----------------
__global__ __launch_bounds__(256) void k_convert_x(const float* __restrict__ x,
                                                   unsigned short* __restrict__ xb) {
    int i = blockIdx.x * 256 + threadIdx.x;        // over n/4 exactly
    float4 v = ((const float4*)x)[i];
    ushort4 o;
    o.x = f2bf(v.x); o.y = f2bf(v.y); o.z = f2bf(v.z); o.w = f2bf(v.w);
    ((ushort4*)xb)[i] = o;
}

// ---------------- Pass 0b: W (I,H,D,3) fp32 -> Wt (3072 x 512) bf16, col-major repack ----------------
__global__ __launch_bounds__(256) void k_repack_w(const float* __restrict__ W,
                                                  unsigned short* __restrict__ Wt) {
    int idx = blockIdx.x * 256 + threadIdx.x;      // over I*H*D*3
    if (idx >= I_ * H_ * D_ * 3) return;
    int kk = idx % 3;
    int d  = (idx / 3) % D_;
    int h  = (idx / (3 * D_)) % H_;
    int i  = idx / (3 * D_ * H_);
    int col = kk * (H_ * D_) + h * D_ + d;         // kk*1024 + h*64 + d
    Wt[(size_t)col * I_ + i] = f2bf(W[idx]);
}

// ---------------- Pass 1: GEMM  C[BT][3072] = A[BT][512] * Wt^T  (bf16 MFMA, 128x128 tile, BK=32) ----------------
__device__ __forceinline__ void load_lds16(const void* g, void* l) {
    __builtin_amdgcn_global_load_lds((const __attribute__((address_space(1))) unsigned int*)g,
                                     (__attribute__((address_space(3))) unsigned int*)l, 16, 0, 0);
}

__global__ __launch_bounds__(256) void k_gemm(const unsigned short* __restrict__ A,
                                              const unsigned short* __restrict__ Bt,
                                              unsigned short* __restrict__ C) {
    __shared__ unsigned short Alds[128 * 32];
    __shared__ unsigned short Blds[128 * 32];   // stored as [n'][k]
    const int tid  = threadIdx.x;
    const int lane = tid & 63;
    const int wave = tid >> 6;
    const int wr = wave >> 1, wc = wave & 1;
    const int cb = blockIdx.x;                  // 0..23  (fastest-varying -> A tiles L2-resident)
    const int rb = blockIdx.y;                  // 0..511
    const int l15 = lane & 15;
    const int kh  = lane >> 4;                  // 0..3

    floatx4 acc[4][4] = {};

    for (int ko = 0; ko < 16; ++ko) {
        const int k0 = ko * 32;
        // stage A and B tiles: each lane loads 16B; LDS dest linear per wave
        #pragma unroll
        for (int it = 0; it < 2; ++it) {
            int lin = it * 256 + wave * 64 + lane;
            int r = lin >> 2;                   // row within tile
            int c = (lin & 3) << 3;             // k within BK
            const unsigned short* srcA = A  + (size_t)(rb * 128 + r) * I_ + k0 + c;
            const unsigned short* srcB = Bt + (size_t)(cb * 128 + r) * I_ + k0 + c;
            load_lds16(srcA, (void*)(Alds + (size_t)(it * 256 + wave * 64) * 8));
            load_lds16(srcB, (void*)(Blds + (size_t)(it * 256 + wave * 64) * 8));
        }
        __syncthreads();

        short8 af[4], bf[4];
        #pragma unroll
        for (int m = 0; m < 4; ++m)
            af[m] = *(const short8*)(Alds + (size_t)(wr * 64 + m * 16 + l15) * 32 + kh * 8);
        #pragma unroll
        for (int n = 0; n < 4; ++n)
            bf[n] = *(const short8*)(Blds + (size_t)(wc * 64 + n * 16 + l15) * 32 + kh * 8);
        #pragma unroll
        for (int m = 0; m < 4; ++m)
            #pragma unroll
            for (int n = 0; n < 4; ++n)
                acc[m][n] = __builtin_amdgcn_mfma_f32_16x16x32_bf16(af[m], bf[n], acc[m][n], 0, 0, 0);
        __syncthreads();
    }

    // epilogue: C/D layout col=lane&15, row=(lane>>4)*4+reg
    #pragma unroll
    for (int m = 0; m < 4; ++m) {
        #pragma unroll
        for (int n = 0; n < 4; ++n) {
            int ccol = cb * 128 + wc * 64 + n * 16 + l15;
            size_t rrow = (size_t)rb * 128 + wr * 64 + m * 16 + kh * 4;
            #pragma unroll
            for (int reg = 0; reg < 4; ++reg)
                C[(rrow + reg) * NCOL + ccol] = f2bf(acc[m][n][reg]);
        }
    }
}

// ---------------- Pass 2: scores s=q.k (parallel) + chunk summaries (max, den-sum, num-sum) ----------------
// One wave per chunk. Critical insight: nothing here is serial over t.
__global__ __launch_bounds__(256) void k_sumchunk(const unsigned short* __restrict__ kvq,
                                                  float* __restrict__ s_out,
                                                  float* __restrict__ m_arr,
                                                  float* __restrict__ d_arr,
                                                  float* __restrict__ n_arr) {
    const int wave = threadIdx.x >> 6, lane = threadIdx.x & 63;
    const int chunk = blockIdx.x * 4 + wave;     // = bh*64 + c
    const int c  = chunk & (CCH - 1);
    const int bh = chunk >> 6;
    const int h  = bh & (H_ - 1);
    const int b  = bh >> 4;

    size_t base = ((size_t)b * T_ + c * LCH) * NCOL + h * D_ + lane;  // k at +0, v +1024, q +2048

    // Pass A: per-t score via wave all-reduce; deposit s_t into lane t
    float sval = -INFINITY;
    #pragma unroll
    for (int t = 0; t < LCH; ++t) {
        float kd = bf2f(kvq[base + (size_t)t * NCOL]);
        float qd = bf2f(kvq[base + (size_t)t * NCOL + 2048]);
        float p = kd * qd;
        #pragma unroll
        for (int off = 32; off; off >>= 1) p += __shfl_xor(p, off);
        if (lane == t) sval = p;
    }
    if (lane < 32) s_out[(size_t)bh * T_ + c * LCH + lane] = sval;

    // chunk max (lanes >=32 hold -inf)
    float M = sval;
    #pragma unroll
    for (int off = 32; off; off >>= 1) M = fmaxf(M, __shfl_xor(M, off));
    // per-t weight on lane t; den-sum
    float wt_l = (lane < 32) ? __expf(sval - M) : 0.f;
    float Dh = wt_l;
    #pragma unroll
    for (int off = 32; off; off >>= 1) Dh += __shfl_xor(Dh, off);

    // Pass B: num-sum over t, lane = d (order-free reduction, 1 FMA/t, independent)
    float Nh = 0.f;
    #pragma unroll
    for (int t = 0; t < LCH; ++t) {
        float vd = bf2f(kvq[base + (size_t)t * NCOL + 1024]);
        float wt = __shfl(wt_l, t);
        Nh += wt * vd;
    }
    if (lane == 0) { m_arr[chunk] = M; d_arr[chunk] = Dh; }
    n_arr[(size_t)chunk * 64 + lane] = Nh;
}

// ---------------- Pass 3: exclusive prefix over chunks; emit fixed-normalizer prefix terms ----------------
// Z_c = max(m_prefix, chunk_max);  pdb = den_prefix*exp(pm-Z);  pnb[d] = num_prefix[d]*exp(pm-Z)
__global__ __launch_bounds__(256) void k_prefix2(const float* __restrict__ m_arr,
                                                 const float* __restrict__ d_arr,
                                                 const float* __restrict__ n_arr,
                                                 float* __restrict__ Zb,
                                                 float* __restrict__ pdb,
                                                 float* __restrict__ pnb) {
    const int wave = threadIdx.x >> 6, lane = threadIdx.x & 63;
    const int bh = blockIdx.x * 4 + wave;        // 0..511
    float m = -INFINITY, den = 0.f, n = 0.f;
    for (int c = 0; c < CCH; ++c) {
        int idx = bh * CCH + c;
        float mc = m_arr[idx], dc = d_arr[idx];
        float nc = n_arr[(size_t)idx * 64 + lane];
        float Z = fmaxf(m, mc);                  // finite (scores finite), even when m=-inf
        float beta = __expf(m - Z);              // 0 when m=-inf
        if (lane == 0) { Zb[idx] = Z; pdb[idx] = den * beta; }
        pnb[(size_t)idx * 64 + lane] = n * beta;
        float a2 = __expf(mc - Z);
        den = den * beta + dc * a2;
        n   = n * beta + nc * a2;
        m = Z;
    }
}

// ---------------- Pass 4: final — 1-FMA serial chain, all exp/rcp parallel, h-sum in LDS ----------------
__global__ __launch_bounds__(1024) void k_final(const unsigned short* __restrict__ kvq,
                                                const float* __restrict__ s_arr,
                                                const float* __restrict__ Zb,
                                                const float* __restrict__ pdb,
                                                const float* __restrict__ pnb,
                                                float* __restrict__ out) {
    __shared__ float accum[LCH * 64];            // 8 KB
    const int tid = threadIdx.x;
    const int h = tid >> 6, lane = tid & 63;
    const int bc = blockIdx.x;                   // b*64 + c
    const int c = bc & (CCH - 1), b = bc >> 6;

    accum[tid] = 0.f;
    accum[tid + 1024] = 0.f;
    __syncthreads();

    const int bh = b * H_ + h;
    const int chain = bh * CCH + c;
    const float Z  = Zb[chain];
    const float pd = pdb[chain];
    const float pnbv = pnb[(size_t)chain * 64 + lane];

    // per-t scalars, computed in parallel on lanes 0..31 (lane = t)
    float sval = (lane < 32) ? s_arr[(size_t)bh * T_ + c * LCH + lane] : 0.f;
    float wv = (lane < 32) ? __expf(sval - Z) : 0.f;
    // inclusive prefix-sum of w over the 32-lane group -> running den
    float cum = wv;
    #pragma unroll
    for (int off = 1; off < 32; off <<= 1) {
        float o = __shfl_up(cum, off, 32);
        if ((lane & 31) >= off) cum += o;
    }
    float rv = __builtin_amdgcn_rcpf(pd + cum);  // r_t = 1/den_t

    float num = 0.f;
    size_t vbase = ((size_t)b * T_ + c * LCH) * NCOL + 1024 + h * D_ + lane;
    #pragma unroll
    for (int t = 0; t < LCH; ++t) {
        float vd = bf2f(kvq[vbase + (size_t)t * NCOL]);
        float wt = __shfl(wv, t);
        float rt = __shfl(rv, t);
        num += wt * vd;                           // the ONLY serial dependency
        atomicAdd(&accum[t * 64 + lane], (pnbv + num) * rt);
    }
    __syncthreads();

    size_t ob = ((size_t)b * T_ + c * LCH) * 64;
    out[ob + tid] = accum[tid];
    out[ob + 1024 + tid] = accum[tid + 1024];
}

// ---------------- launch ----------------
extern "C" void kernel_launch(void* const* d_in, const int* in_sizes, int n_in,
                              void* d_out, int out_size, void* d_ws, size_t ws_size,
                              hipStream_t stream) {
    const float* x = (const float*)d_in[0];
    const float* W = (const float*)d_in[1];
    float* out = (float*)d_out;
    char* ws = (char*)d_ws;

    // workspace layout (bytes)
    unsigned short* kvq = (unsigned short*)(ws);                 // 402,653,184
    unsigned short* xb  = (unsigned short*)(ws + 402653184ull);  //  67,108,864
    unsigned short* Wt  = (unsigned short*)(ws + 469762048ull);  //   3,145,728 -> end 472,907,776
    // scan scratch overlaid onto xb (xb dead after k_gemm):
    char* sb = ws + 402653184ull;
    float* s_arr = (float*)(sb);                                 //   4,194,304
    float* m_arr = (float*)(sb + 4194304ull);                    //     131,072
    float* d_arr = (float*)(sb + 4325376ull);                    //     131,072
    float* n_arr = (float*)(sb + 4456448ull);                    //   8,388,608
    float* Zb    = (float*)(sb + 12845056ull);                   //     131,072
    float* pdb   = (float*)(sb + 12976128ull);                   //     131,072
    float* pnb   = (float*)(sb + 13107200ull);                   //   8,388,608  (21.5 MB < 67 MB xb)

    k_convert_x<<<(BT * I_ / 4) / 256, 256, 0, stream>>>(x, xb);
    k_repack_w<<<(I_ * H_ * D_ * 3 + 255) / 256, 256, 0, stream>>>(W, Wt);
    k_gemm<<<dim3(NCOL / 128, BT / 128), 256, 0, stream>>>(xb, Wt, kvq);
    k_sumchunk<<<(B_ * H_ * CCH) / 4, 256, 0, stream>>>(kvq, s_arr, m_arr, d_arr, n_arr);
    k_prefix2<<<(B_ * H_) / 4, 256, 0, stream>>>(m_arr, d_arr, n_arr, Zb, pdb, pnb);
    k_final<<<B_ * CCH, 1024, 0, stream>>>(kvq, s_arr, Zb, pdb, pnb, out);
}

// Round 6
// 690.046 us; speedup vs baseline: 1.4580x; 1.4002x over previous
//
#include <hip/hip_runtime.h>
#include <stdint.h>

// Problem dims (fixed by reference setup_inputs)
#define B_   32
#define T_   2048
#define I_   512
#define H_   16
#define D_   64
#define BT   (B_*T_)        // 65536 rows
#define NCOL (3*H_*D_)      // 3072 gemm cols: col' = kk*1024 + h*64 + d  (kk: 0=k,1=v,2=q)
#define CCH  64             // chunks per (b,h) chain
#define LCH  (T_/CCH)       // 32 timesteps per chunk

typedef short short8 __attribute__((ext_vector_type(8)));
typedef float floatx4 __attribute__((ext_vector_type(4)));

__device__ __forceinline__ unsigned short f2bf(float f) {
    uint32_t u = __float_as_uint(f);
    u = (u + 0x7FFFu + ((u >> 16) & 1u)) >> 16;   // RNE
    return (unsigned short)u;
}
__device__ __forceinline__ float bf2f(unsigned short u) {
    return __uint_as_float(((uint32_t)u) << 16);
}

// ---------------- Pass 0a: x fp32 -> bf16 ----------------
__global__ __launch_bounds__(256) void k_convert_x(const float* __restrict__ x,
                                                   unsigned short* __restrict__ xb) {
    int i = blockIdx.x * 256 + threadIdx.x;        // over n/4 exactly
    float4 v = ((const float4*)x)[i];
    ushort4 o;
    o.x = f2bf(v.x); o.y = f2bf(v.y); o.z = f2bf(v.z); o.w = f2bf(v.w);
    ((ushort4*)xb)[i] = o;
}

// ---------------- Pass 0b: W (I,H,D,3) fp32 -> Wt (3072 x 512) bf16, col-major repack ----------------
__global__ __launch_bounds__(256) void k_repack_w(const float* __restrict__ W,
                                                  unsigned short* __restrict__ Wt) {
    int idx = blockIdx.x * 256 + threadIdx.x;      // over I*H*D*3
    if (idx >= I_ * H_ * D_ * 3) return;
    int kk = idx % 3;
    int d  = (idx / 3) % D_;
    int h  = (idx / (3 * D_)) % H_;
    int i  = idx / (3 * D_ * H_);
    int col = kk * (H_ * D_) + h * D_ + d;         // kk*1024 + h*64 + d
    Wt[(size_t)col * I_ + i] = f2bf(W[idx]);
}

// ---------------- Pass 1: GEMM  C[BT][3072] = A[BT][512] * Wt^T  (bf16 MFMA, 128x128 tile, BK=32) ----------------
__device__ __forceinline__ void load_lds16(const void* g, void* l) {
    __builtin_amdgcn_global_load_lds((const __attribute__((address_space(1))) unsigned int*)g,
                                     (__attribute__((address_space(3))) unsigned int*)l, 16, 0, 0);
}

__global__ __launch_bounds__(256) void k_gemm(const unsigned short* __restrict__ A,
                                              const unsigned short* __restrict__ Bt,
                                              unsigned short* __restrict__ C) {
    __shared__ unsigned short Alds[128 * 32];
    __shared__ unsigned short Blds[128 * 32];   // stored as [n'][k]
    const int tid  = threadIdx.x;
    const int lane = tid & 63;
    const int wave = tid >> 6;
    const int wr = wave >> 1, wc = wave & 1;
    const int cb = blockIdx.x;                  // 0..23  (fastest-varying -> A tiles L2-resident)
    const int rb = blockIdx.y;                  // 0..511
    const int l15 = lane & 15;
    const int kh  = lane >> 4;                  // 0..3

    floatx4 acc[4][4] = {};

    for (int ko = 0; ko < 16; ++ko) {
        const int k0 = ko * 32;
        // stage A and B tiles: each lane loads 16B; LDS dest linear per wave
        #pragma unroll
        for (int it = 0; it < 2; ++it) {
            int lin = it * 256 + wave * 64 + lane;
            int r = lin >> 2;                   // row within tile
            int c = (lin & 3) << 3;             // k within BK
            const unsigned short* srcA = A  + (size_t)(rb * 128 + r) * I_ + k0 + c;
            const unsigned short* srcB = Bt + (size_t)(cb * 128 + r) * I_ + k0 + c;
            load_lds16(srcA, (void*)(Alds + (size_t)(it * 256 + wave * 64) * 8));
            load_lds16(srcB, (void*)(Blds + (size_t)(it * 256 + wave * 64) * 8));
        }
        __syncthreads();

        short8 af[4], bf[4];
        #pragma unroll
        for (int m = 0; m < 4; ++m)
            af[m] = *(const short8*)(Alds + (size_t)(wr * 64 + m * 16 + l15) * 32 + kh * 8);
        #pragma unroll
        for (int n = 0; n < 4; ++n)
            bf[n] = *(const short8*)(Blds + (size_t)(wc * 64 + n * 16 + l15) * 32 + kh * 8);
        #pragma unroll
        for (int m = 0; m < 4; ++m)
            #pragma unroll
            for (int n = 0; n < 4; ++n)
                acc[m][n] = __builtin_amdgcn_mfma_f32_16x16x32_bf16(af[m], bf[n], acc[m][n], 0, 0, 0);
        __syncthreads();
    }

    // epilogue: C/D layout col=lane&15, row=(lane>>4)*4+reg
    #pragma unroll
    for (int m = 0; m < 4; ++m) {
        #pragma unroll
        for (int n = 0; n < 4; ++n) {
            int ccol = cb * 128 + wc * 64 + n * 16 + l15;
            size_t rrow = (size_t)rb * 128 + wr * 64 + m * 16 + kh * 4;
            #pragma unroll
            for (int reg = 0; reg < 4; ++reg)
                C[(rrow + reg) * NCOL + ccol] = f2bf(acc[m][n][reg]);
        }
    }
}

// ---------------- Pass 2: scores s=q.k (parallel) + chunk summaries (max, den-sum, num-sum) ----------------
// One wave per chunk. Critical insight: nothing here is serial over t.
__global__ __launch_bounds__(256) void k_sumchunk(const unsigned short* __restrict__ kvq,
                                                  float* __restrict__ s_out,
                                                  float* __restrict__ m_arr,
                                                  float* __restrict__ d_arr,
                                                  float* __restrict__ n_arr) {
    const int wave = threadIdx.x >> 6, lane = threadIdx.x & 63;
    const int chunk = blockIdx.x * 4 + wave;     // = bh*64 + c
    const int c  = chunk & (CCH - 1);
    const int bh = chunk >> 6;
    const int h  = bh & (H_ - 1);
    const int b  = bh >> 4;

    size_t base = ((size_t)b * T_ + c * LCH) * NCOL + h * D_ + lane;  // k at +0, v +1024, q +2048

    // Pass A: per-t score via wave all-reduce; deposit s_t into lane t
    float sval = -INFINITY;
    #pragma unroll
    for (int t = 0; t < LCH; ++t) {
        float kd = bf2f(kvq[base + (size_t)t * NCOL]);
        float qd = bf2f(kvq[base + (size_t)t * NCOL + 2048]);
        float p = kd * qd;
        #pragma unroll
        for (int off = 32; off; off >>= 1) p += __shfl_xor(p, off);
        if (lane == t) sval = p;
    }
    if (lane < 32) s_out[(size_t)bh * T_ + c * LCH + lane] = sval;

    // chunk max (lanes >=32 hold -inf)
    float M = sval;
    #pragma unroll
    for (int off = 32; off; off >>= 1) M = fmaxf(M, __shfl_xor(M, off));
    // per-t weight on lane t; den-sum
    float wt_l = (lane < 32) ? __expf(sval - M) : 0.f;
    float Dh = wt_l;
    #pragma unroll
    for (int off = 32; off; off >>= 1) Dh += __shfl_xor(Dh, off);

    // Pass B: num-sum over t, lane = d (order-free reduction, 1 FMA/t, independent)
    float Nh = 0.f;
    #pragma unroll
    for (int t = 0; t < LCH; ++t) {
        float vd = bf2f(kvq[base + (size_t)t * NCOL + 1024]);
        float wt = __shfl(wt_l, t);
        Nh += wt * vd;
    }
    if (lane == 0) { m_arr[chunk] = M; d_arr[chunk] = Dh; }
    n_arr[(size_t)chunk * 64 + lane] = Nh;
}

// ---------------- Pass 3: exclusive prefix over chunks; emit fixed-normalizer prefix terms ----------------
// Z_c = max(m_prefix, chunk_max);  pdb = den_prefix*exp(pm-Z);  pnb[d] = num_prefix[d]*exp(pm-Z)
__global__ __launch_bounds__(256) void k_prefix2(const float* __restrict__ m_arr,
                                                 const float* __restrict__ d_arr,
                                                 const float* __restrict__ n_arr,
                                                 float* __restrict__ Zb,
                                                 float* __restrict__ pdb,
                                                 float* __restrict__ pnb) {
    const int wave = threadIdx.x >> 6, lane = threadIdx.x & 63;
    const int bh = blockIdx.x * 4 + wave;        // 0..511
    float m = -INFINITY, den = 0.f, n = 0.f;
    for (int c = 0; c < CCH; ++c) {
        int idx = bh * CCH + c;
        float mc = m_arr[idx], dc = d_arr[idx];
        float nc = n_arr[(size_t)idx * 64 + lane];
        float Z = fmaxf(m, mc);                  // finite (scores finite), even when m=-inf
        float beta = __expf(m - Z);              // 0 when m=-inf
        if (lane == 0) { Zb[idx] = Z; pdb[idx] = den * beta; }
        pnb[(size_t)idx * 64 + lane] = n * beta;
        float a2 = __expf(mc - Z);
        den = den * beta + dc * a2;
        n   = n * beta + nc * a2;
        m = Z;
    }
}

// ---------------- Pass 4: final — register accumulation over 4 heads/wave, LDS tree-sum (NO atomics) ----------------
__global__ __launch_bounds__(256) void k_final(const unsigned short* __restrict__ kvq,
                                               const float* __restrict__ s_arr,
                                               const float* __restrict__ Zb,
                                               const float* __restrict__ pdb,
                                               const float* __restrict__ pnb,
                                               float* __restrict__ out) {
    __shared__ float red[4][LCH * 64];           // 32 KB, one slab per wave
    const int tid = threadIdx.x;
    const int wave = tid >> 6, lane = tid & 63;
    const int bc = blockIdx.x;                   // b*64 + c
    const int c = bc & (CCH - 1), b = bc >> 6;

    float csum[LCH];
    #pragma unroll
    for (int t = 0; t < LCH; ++t) csum[t] = 0.f;

    #pragma unroll
    for (int hh = 0; hh < 4; ++hh) {
        const int h = wave * 4 + hh;
        const int bh = b * H_ + h;
        const int chain = bh * CCH + c;
        const float Z  = Zb[chain];
        const float pd = pdb[chain];
        const float pnbv = pnb[(size_t)chain * 64 + lane];

        // per-t scalars, computed in parallel on lanes 0..31 (lane = t)
        float sval = (lane < 32) ? s_arr[(size_t)bh * T_ + c * LCH + lane] : 0.f;
        float wv = (lane < 32) ? __expf(sval - Z) : 0.f;
        // inclusive prefix-sum of w over the 32-lane group -> running den
        float cum = wv;
        #pragma unroll
        for (int off = 1; off < 32; off <<= 1) {
            float o = __shfl_up(cum, off, 32);
            if ((lane & 31) >= off) cum += o;
        }
        float rv = __builtin_amdgcn_rcpf(pd + cum);  // r_t = 1/den_t

        float num = 0.f;
        size_t vbase = ((size_t)b * T_ + c * LCH) * NCOL + 1024 + h * D_ + lane;
        #pragma unroll
        for (int t = 0; t < LCH; ++t) {
            float vd = bf2f(kvq[vbase + (size_t)t * NCOL]);
            float wt = __shfl(wv, t);
            float rt = __shfl(rv, t);
            num += wt * vd;                       // the ONLY serial dependency
            csum[t] += (pnbv + num) * rt;
        }
    }

    // deterministic cross-wave reduction: stage 4 wave-slabs, then 4-way add
    #pragma unroll
    for (int t = 0; t < LCH; ++t)
        red[wave][t * 64 + lane] = csum[t];
    __syncthreads();

    size_t ob = ((size_t)b * T_ + c * LCH) * 64;
    #pragma unroll
    for (int i = 0; i < 8; ++i) {
        int idx = i * 256 + tid;
        out[ob + idx] = red[0][idx] + red[1][idx] + red[2][idx] + red[3][idx];
    }
}

// ---------------- launch ----------------
extern "C" void kernel_launch(void* const* d_in, const int* in_sizes, int n_in,
                              void* d_out, int out_size, void* d_ws, size_t ws_size,
                              hipStream_t stream) {
    const float* x = (const float*)d_in[0];
    const float* W = (const float*)d_in[1];
    float* out = (float*)d_out;
    char* ws = (char*)d_ws;

    // workspace layout (bytes)
    unsigned short* kvq = (unsigned short*)(ws);                 // 402,653,184
    unsigned short* xb  = (unsigned short*)(ws + 402653184ull);  //  67,108,864
    unsigned short* Wt  = (unsigned short*)(ws + 469762048ull);  //   3,145,728 -> end 472,907,776
    // scan scratch overlaid onto xb (xb dead after k_gemm):
    char* sb = ws + 402653184ull;
    float* s_arr = (float*)(sb);                                 //   4,194,304
    float* m_arr = (float*)(sb + 4194304ull);                    //     131,072
    float* d_arr = (float*)(sb + 4325376ull);                    //     131,072
    float* n_arr = (float*)(sb + 4456448ull);                    //   8,388,608
    float* Zb    = (float*)(sb + 12845056ull);                   //     131,072
    float* pdb   = (float*)(sb + 12976128ull);                   //     131,072
    float* pnb   = (float*)(sb + 13107200ull);                   //   8,388,608  (21.5 MB < 67 MB xb)

    k_convert_x<<<(BT * I_ / 4) / 256, 256, 0, stream>>>(x, xb);
    k_repack_w<<<(I_ * H_ * D_ * 3 + 255) / 256, 256, 0, stream>>>(W, Wt);
    k_gemm<<<dim3(NCOL / 128, BT / 128), 256, 0, stream>>>(xb, Wt, kvq);
    k_sumchunk<<<(B_ * H_ * CCH) / 4, 256, 0, stream>>>(kvq, s_arr, m_arr, d_arr, n_arr);
    k_prefix2<<<(B_ * H_) / 4, 256, 0, stream>>>(m_arr, d_arr, n_arr, Zb, pdb, pnb);
    k_final<<<B_ * CCH, 256, 0, stream>>>(kvq, s_arr, Zb, pdb, pnb, out);
}

// Round 8
// 546.718 us; speedup vs baseline: 1.8403x; 1.2622x over previous
//
#include <hip/hip_runtime.h>
#include <stdint.h>

// Problem dims (fixed by reference setup_inputs)
#define B_   32
#define T_   2048
#define I_   512
#define H_   16
#define D_   64
#define BT   (B_*T_)        // 65536 rows
#define CCH  64             // chunks per (b,h) chain
#define LCH  (T_/CCH)       // 32 timesteps per chunk

// GEMM col layout (3072 cols of Wt):
//   cols h*128 + d        : k of head h   (h<16)          -> consumed in-epilogue (scores)
//   cols h*128 + 64 + d   : q of head h                   -> consumed in-epilogue
//   cols 2048 + h*64 + d  : v of head h                   -> written to Vb[BT][1024]

typedef short short8 __attribute__((ext_vector_type(8)));
typedef float floatx4 __attribute__((ext_vector_type(4)));

__device__ __forceinline__ unsigned short f2bf(float f) {
    uint32_t u = __float_as_uint(f);
    u = (u + 0x7FFFu + ((u >> 16) & 1u)) >> 16;   // RNE
    return (unsigned short)u;
}
__device__ __forceinline__ float bf2f(unsigned short u) {
    return __uint_as_float(((uint32_t)u) << 16);
}

// ---------------- Pass 0a: x fp32 -> bf16 ----------------
__global__ __launch_bounds__(256) void k_convert_x(const float* __restrict__ x,
                                                   unsigned short* __restrict__ xb) {
    int i = blockIdx.x * 256 + threadIdx.x;        // over n/4 exactly
    float4 v = ((const float4*)x)[i];
    ushort4 o;
    o.x = f2bf(v.x); o.y = f2bf(v.y); o.z = f2bf(v.z); o.w = f2bf(v.w);
    ((ushort4*)xb)[i] = o;
}

// ---------------- Pass 0b: W (I,H,D,3) fp32 -> Wt (3072 x 512) bf16, head-paired repack ----------------
__global__ __launch_bounds__(256) void k_repack_w(const float* __restrict__ W,
                                                  unsigned short* __restrict__ Wt) {
    int idx = blockIdx.x * 256 + threadIdx.x;      // over I*H*D*3
    if (idx >= I_ * H_ * D_ * 3) return;
    int kk = idx % 3;                              // 0=k, 1=v, 2=q
    int d  = (idx / 3) % D_;
    int h  = (idx / (3 * D_)) % H_;
    int i  = idx / (3 * D_ * H_);
    int col = (kk == 1) ? (2048 + h * 64 + d)
                        : (h * 128 + d + (kk == 2 ? 64 : 0));
    Wt[(size_t)col * I_ + i] = f2bf(W[idx]);
}

// ---------------- Pass 1: GEMM with fused q.k scores ----------------
__device__ __forceinline__ void load_lds16(const void* g, void* l) {
    __builtin_amdgcn_global_load_lds((const __attribute__((address_space(1))) unsigned int*)g,
                                     (__attribute__((address_space(3))) unsigned int*)l, 16, 0, 0);
}

__global__ __launch_bounds__(256) void k_gemm(const unsigned short* __restrict__ A,
                                              const unsigned short* __restrict__ Bt,
                                              unsigned short* __restrict__ Vb,
                                              float* __restrict__ s_arr) {
    __shared__ unsigned short Alds[128 * 32];
    __shared__ unsigned short Blds[128 * 32];   // [n'][k]
    const int tid  = threadIdx.x;
    const int lane = tid & 63;
    const int wave = tid >> 6;
    const int cb = blockIdx.x;                  // 0..15 score(head cb), 16..23 v
    const int rb = blockIdx.y;                  // 0..511
    const int l15 = lane & 15;
    const int kh  = lane >> 4;                  // 0..3

    if (cb < 16) {
        // ---- score block: 4 waves x (32 rows x 128 cols), acc[m<2][n<8] ----
        floatx4 acc[2][8] = {};
        for (int ko = 0; ko < 16; ++ko) {
            const int k0 = ko * 32;
            #pragma unroll
            for (int it = 0; it < 2; ++it) {
                int lin = it * 256 + wave * 64 + lane;
                int r = lin >> 2;
                int c = (lin & 3) << 3;
                load_lds16(A  + (size_t)(rb * 128 + r) * I_ + k0 + c,
                           (void*)(Alds + (size_t)(it * 256 + wave * 64) * 8));
                load_lds16(Bt + (size_t)(cb * 128 + r) * I_ + k0 + c,
                           (void*)(Blds + (size_t)(it * 256 + wave * 64) * 8));
            }
            __syncthreads();
            short8 af[2], bfr[8];
            #pragma unroll
            for (int m = 0; m < 2; ++m)
                af[m] = *(const short8*)(Alds + (size_t)(wave * 32 + m * 16 + l15) * 32 + kh * 8);
            #pragma unroll
            for (int n = 0; n < 8; ++n)
                bfr[n] = *(const short8*)(Blds + (size_t)(n * 16 + l15) * 32 + kh * 8);
            #pragma unroll
            for (int m = 0; m < 2; ++m)
                #pragma unroll
                for (int n = 0; n < 8; ++n)
                    acc[m][n] = __builtin_amdgcn_mfma_f32_16x16x32_bf16(af[m], bfr[n], acc[m][n], 0, 0, 0);
            __syncthreads();
        }
        // fused s = sum_d k[r,d]*q[r,d]: frag n (cols n*16+l15) pairs with frag n+4 (cols 64+n*16+l15)
        float sacc[2][4];
        #pragma unroll
        for (int m = 0; m < 2; ++m)
            #pragma unroll
            for (int reg = 0; reg < 4; ++reg) {
                float s = 0.f;
                #pragma unroll
                for (int n = 0; n < 4; ++n)
                    s += acc[m][n][reg] * acc[m][n + 4][reg];
                sacc[m][reg] = s;
            }
        // reduce over the 16 l15 lanes (same rows, different cols)
        #pragma unroll
        for (int m = 0; m < 2; ++m)
            #pragma unroll
            for (int reg = 0; reg < 4; ++reg) {
                float s = sacc[m][reg];
                s += __shfl_xor(s, 1);
                s += __shfl_xor(s, 2);
                s += __shfl_xor(s, 4);
                s += __shfl_xor(s, 8);
                sacc[m][reg] = s;
            }
        // lane l15 = m*4+reg (l15<8) stores row wave*32 + m*16 + kh*4 + reg
        float sv = sacc[0][0];
        #pragma unroll
        for (int m = 0; m < 2; ++m)
            #pragma unroll
            for (int reg = 0; reg < 4; ++reg)
                if (l15 == m * 4 + reg) sv = sacc[m][reg];
        if (l15 < 8) {
            int row = rb * 128 + wave * 32 + (l15 >> 2) * 16 + kh * 4 + (l15 & 3);
            int b = row >> 11, t = row & 2047;
            s_arr[((size_t)(b * H_ + cb) << 11) + t] = sv;
        }
    } else {
        // ---- v block: 2x2 waves x (64x64), acc[4][4]; write Vb ----
        const int wr = wave >> 1, wc = wave & 1;
        floatx4 acc[4][4] = {};
        for (int ko = 0; ko < 16; ++ko) {
            const int k0 = ko * 32;
            #pragma unroll
            for (int it = 0; it < 2; ++it) {
                int lin = it * 256 + wave * 64 + lane;
                int r = lin >> 2;
                int c = (lin & 3) << 3;
                load_lds16(A  + (size_t)(rb * 128 + r) * I_ + k0 + c,
                           (void*)(Alds + (size_t)(it * 256 + wave * 64) * 8));
                load_lds16(Bt + (size_t)(cb * 128 + r) * I_ + k0 + c,
                           (void*)(Blds + (size_t)(it * 256 + wave * 64) * 8));
            }
            __syncthreads();
            short8 af[4], bfr[4];
            #pragma unroll
            for (int m = 0; m < 4; ++m)
                af[m] = *(const short8*)(Alds + (size_t)(wr * 64 + m * 16 + l15) * 32 + kh * 8);
            #pragma unroll
            for (int n = 0; n < 4; ++n)
                bfr[n] = *(const short8*)(Blds + (size_t)(wc * 64 + n * 16 + l15) * 32 + kh * 8);
            #pragma unroll
            for (int m = 0; m < 4; ++m)
                #pragma unroll
                for (int n = 0; n < 4; ++n)
                    acc[m][n] = __builtin_amdgcn_mfma_f32_16x16x32_bf16(af[m], bfr[n], acc[m][n], 0, 0, 0);
            __syncthreads();
        }
        #pragma unroll
        for (int m = 0; m < 4; ++m) {
            #pragma unroll
            for (int n = 0; n < 4; ++n) {
                int vcol = (cb - 16) * 128 + wc * 64 + n * 16 + l15;
                size_t rrow = (size_t)rb * 128 + wr * 64 + m * 16 + kh * 4;
                #pragma unroll
                for (int reg = 0; reg < 4; ++reg)
                    Vb[(rrow + reg) * 1024 + vcol] = f2bf(acc[m][n][reg]);
            }
        }
    }
}

// ---------------- Pass 2: chunk summaries from s + v (max, den-sum, num-sum) ----------------
__global__ __launch_bounds__(256) void k_sumchunk(const unsigned short* __restrict__ Vb,
                                                  const float* __restrict__ s_arr,
                                                  float* __restrict__ m_arr,
                                                  float* __restrict__ d_arr,
                                                  float* __restrict__ n_arr) {
    const int wave = threadIdx.x >> 6, lane = threadIdx.x & 63;
    const int chunk = blockIdx.x * 4 + wave;     // = bh*64 + c
    const int c  = chunk & (CCH - 1);
    const int bh = chunk >> 6;
    const int h  = bh & (H_ - 1);
    const int b  = bh >> 4;

    float sval = (lane < 32) ? s_arr[(size_t)bh * T_ + c * LCH + lane] : -INFINITY;
    float M = sval;
    #pragma unroll
    for (int off = 32; off; off >>= 1) M = fmaxf(M, __shfl_xor(M, off));
    float wt_l = (lane < 32) ? __expf(sval - M) : 0.f;
    float Dh = wt_l;
    #pragma unroll
    for (int off = 32; off; off >>= 1) Dh += __shfl_xor(Dh, off);

    float Nh = 0.f;
    size_t base_v = ((size_t)b * T_ + c * LCH) * 1024 + h * D_ + lane;
    #pragma unroll
    for (int t = 0; t < LCH; ++t) {
        float vd = bf2f(Vb[base_v + (size_t)t * 1024]);
        Nh += __shfl(wt_l, t) * vd;
    }
    if (lane == 0) { m_arr[chunk] = M; d_arr[chunk] = Dh; }
    n_arr[(size_t)chunk * 64 + lane] = Nh;
}

// ---------------- Pass 3: exclusive prefix over chunks; fixed-normalizer prefix terms ----------------
__global__ __launch_bounds__(256) void k_prefix2(const float* __restrict__ m_arr,
                                                 const float* __restrict__ d_arr,
                                                 const float* __restrict__ n_arr,
                                                 float* __restrict__ Zb,
                                                 float* __restrict__ pdb,
                                                 float* __restrict__ pnb) {
    const int wave = threadIdx.x >> 6, lane = threadIdx.x & 63;
    const int bh = blockIdx.x * 4 + wave;        // 0..511
    float m = -INFINITY, den = 0.f, n = 0.f;
    for (int c = 0; c < CCH; ++c) {
        int idx = bh * CCH + c;
        float mc = m_arr[idx], dc = d_arr[idx];
        float nc = n_arr[(size_t)idx * 64 + lane];
        float Z = fmaxf(m, mc);
        float beta = __expf(m - Z);
        if (lane == 0) { Zb[idx] = Z; pdb[idx] = den * beta; }
        pnb[(size_t)idx * 64 + lane] = n * beta;
        float a2 = __expf(mc - Z);
        den = den * beta + dc * a2;
        n   = n * beta + nc * a2;
        m = Z;
    }
}

// ---------------- Pass 4: final — register accumulation, LDS tree-sum (no atomics) ----------------
__global__ __launch_bounds__(256) void k_final(const unsigned short* __restrict__ Vb,
                                               const float* __restrict__ s_arr,
                                               const float* __restrict__ Zb,
                                               const float* __restrict__ pdb,
                                               const float* __restrict__ pnb,
                                               float* __restrict__ out) {
    __shared__ float red[4][LCH * 64];           // 32 KB
    const int tid = threadIdx.x;
    const int wave = tid >> 6, lane = tid & 63;
    const int bc = blockIdx.x;                   // b*64 + c
    const int c = bc & (CCH - 1), b = bc >> 6;

    float csum[LCH];
    #pragma unroll
    for (int t = 0; t < LCH; ++t) csum[t] = 0.f;

    #pragma unroll
    for (int hh = 0; hh < 4; ++hh) {
        const int h = wave * 4 + hh;
        const int bh = b * H_ + h;
        const int chain = bh * CCH + c;
        const float Z  = Zb[chain];
        const float pd = pdb[chain];
        const float pnbv = pnb[(size_t)chain * 64 + lane];

        float sval = (lane < 32) ? s_arr[(size_t)bh * T_ + c * LCH + lane] : 0.f;
        float wv = (lane < 32) ? __expf(sval - Z) : 0.f;
        float cum = wv;
        #pragma unroll
        for (int off = 1; off < 32; off <<= 1) {
            float o = __shfl_up(cum, off, 32);
            if ((lane & 31) >= off) cum += o;
        }
        float rv = __builtin_amdgcn_rcpf(pd + cum);  // 1/den_t

        float num = 0.f;
        size_t vbase = ((size_t)b * T_ + c * LCH) * 1024 + h * D_ + lane;
        #pragma unroll
        for (int t = 0; t < LCH; ++t) {
            float vd = bf2f(Vb[vbase + (size_t)t * 1024]);
            float wt = __shfl(wv, t);
            float rt = __shfl(rv, t);
            num += wt * vd;                       // the ONLY serial dependency
            csum[t] += (pnbv + num) * rt;
        }
    }

    #pragma unroll
    for (int t = 0; t < LCH; ++t)
        red[wave][t * 64 + lane] = csum[t];
    __syncthreads();

    size_t ob = ((size_t)b * T_ + c * LCH) * 64;
    #pragma unroll
    for (int i = 0; i < 8; ++i) {
        int idx = i * 256 + tid;
        out[ob + idx] = red[0][idx] + red[1][idx] + red[2][idx] + red[3][idx];
    }
}

// ---------------- launch ----------------
extern "C" void kernel_launch(void* const* d_in, const int* in_sizes, int n_in,
                              void* d_out, int out_size, void* d_ws, size_t ws_size,
                              hipStream_t stream) {
    const float* x = (const float*)d_in[0];
    const float* W = (const float*)d_in[1];
    float* out = (float*)d_out;
    char* ws = (char*)d_ws;

    // workspace layout (bytes)
    unsigned short* Vb  = (unsigned short*)(ws);                 // 134,217,728
    unsigned short* xb  = (unsigned short*)(ws + 134217728ull);  //  67,108,864
    unsigned short* Wt  = (unsigned short*)(ws + 201326592ull);  //   3,145,728
    float* s_arr = (float*)(ws + 204472320ull);                  //   4,194,304
    float* m_arr = (float*)(ws + 208666624ull);                  //     131,072
    float* d_arr = (float*)(ws + 208797696ull);                  //     131,072
    float* n_arr = (float*)(ws + 208928768ull);                  //   8,388,608
    float* Zb    = (float*)(ws + 217317376ull);                  //     131,072
    float* pdb   = (float*)(ws + 217448448ull);                  //     131,072
    float* pnb   = (float*)(ws + 217579520ull);                  //   8,388,608 -> end 225,968,128

    k_convert_x<<<(BT * I_ / 4) / 256, 256, 0, stream>>>(x, xb);
    k_repack_w<<<(I_ * H_ * D_ * 3 + 255) / 256, 256, 0, stream>>>(W, Wt);
    k_gemm<<<dim3(24, BT / 128), 256, 0, stream>>>(xb, Wt, Vb, s_arr);
    k_sumchunk<<<(B_ * H_ * CCH) / 4, 256, 0, stream>>>(Vb, s_arr, m_arr, d_arr, n_arr);
    k_prefix2<<<(B_ * H_) / 4, 256, 0, stream>>>(m_arr, d_arr, n_arr, Zb, pdb, pnb);
    k_final<<<B_ * CCH, 256, 0, stream>>>(Vb, s_arr, Zb, pdb, pnb, out);
}